// Round 14
// baseline (260.656 us; speedup 1.0000x reference)
//
#include <hip/hip_runtime.h>
#include <hip/hip_bf16.h>

// Problem constants
constexpr int NN = 100000;       // nodes
constexpr int NE = 1600000;      // edges
constexpr int NG = 512;          // graphs
constexpr int IND = 384;         // in dim
constexpr int HD  = 128;         // hidden dim

// CSR bucket geometry: fixed-capacity slots -> no chunk-prefix pass needed.
constexpr int NR      = 128;             // node ranges
constexpr int RSPAN   = 782;             // nodes per range (128*782 >= NN)
constexpr int CHUNKS  = 800;             // edge chunks
constexpr int CHUNK_E = NE / CHUNKS;     // 2000 edges per chunk
constexpr int SLOT    = 64;              // capacity per (chunk,range); Poisson(15.6), P(>64)~1e-17
constexpr int ENT_MAX = 13504;           // per-range packed entries (mean 12512, +9 sigma)

typedef short bf16x8 __attribute__((ext_vector_type(8)));
typedef float f32x4  __attribute__((ext_vector_type(4)));
typedef float f32x2  __attribute__((ext_vector_type(2)));

__device__ __forceinline__ unsigned short f2bf(float x) {
    unsigned int u = __builtin_bit_cast(unsigned int, x);
    u = (u + 0x7FFFu + ((u >> 16) & 1u)) >> 16;   // RNE
    return (unsigned short)u;
}
__device__ __forceinline__ float bf2f(unsigned short v) {
    return __builtin_bit_cast(float, (unsigned int)v << 16);
}
// fp8 e4m3 (OCP) encode/decode via gfx950 HW converts
__device__ __forceinline__ unsigned char f2fp8(float v) {
    return (unsigned char)(__builtin_amdgcn_cvt_pk_fp8_f32(v, 0.0f, 0, false) & 0xFF);
}

// ---------------------------------------------------------------------------
// MFMA bf16 GEMM: Cout[M x 128](fp8 e4m3) = dinv[row] * (A @ Wt^T)
// AMODE: 0 = A fp32 ; 2 = A fp8 e4m3. Wt is [128][K] bf16.
// 128x128 tile, BK=64, 4 waves each owning a 64x64 quadrant (4x4 16x16 frags).
// Register-prefetch of the next K-tile's A overlaps HBM latency with MFMA.
// NOTE (r10 lesson): keep UNFUSED from scatter work — 37.9KB-LDS blocks cap
// occupancy and strangle latency-bound blocks co-scheduled with them.
template <int K, int AMODE>
__global__ __launch_bounds__(256) void k_gemm_mfma(const void* __restrict__ Av,
                                                   const unsigned short* __restrict__ Wt,
                                                   const float* __restrict__ dinv,
                                                   unsigned char* __restrict__ Cout,
                                                   int M) {
    __shared__ unsigned short As[128][72];   // rows padded: stride 144B
    __shared__ unsigned short Bs[128][72];   // Bs[n][k]
    const int tid  = threadIdx.x;
    const int lane = tid & 63;
    const int wid  = tid >> 6;
    const int wm   = (wid & 1) * 64;
    const int wn   = (wid >> 1) * 64;
    const int m0   = blockIdx.x * 128;

    f32x4 acc[4][4];
#pragma unroll
    for (int i = 0; i < 4; ++i)
#pragma unroll
        for (int j = 0; j < 4; ++j) acc[i][j] = f32x4{0.f, 0.f, 0.f, 0.f};

    const int cg = tid & 15;      // A col group (4 elems)
    const int rb = tid >> 4;      // A row base 0..15
    const int wrow = tid >> 1;    // Wt row 0..127
    const int wh   = tid & 1;     // Wt 32-col half

    float4 a_cur[8], a_nxt[8];
    auto loadA = [&](int k0, float4* dst) {
#pragma unroll
        for (int p = 0; p < 8; ++p) {
            int gr = m0 + rb + p * 16; if (gr > M - 1) gr = M - 1;
            if (AMODE == 0) {
                dst[p] = *(const float4*)((const float*)Av + (size_t)gr * K + k0 + cg * 4);
            } else {
                unsigned u = *(const unsigned*)((const unsigned char*)Av +
                                                (size_t)gr * K + k0 + cg * 4);
                f32x2 lo = __builtin_amdgcn_cvt_pk_f32_fp8((int)u, false);
                f32x2 hi = __builtin_amdgcn_cvt_pk_f32_fp8((int)u, true);
                dst[p].x = lo[0]; dst[p].y = lo[1]; dst[p].z = hi[0]; dst[p].w = hi[1];
            }
        }
    };

    loadA(0, a_cur);
    for (int k0 = 0; k0 < K; k0 += 64) {
#pragma unroll
        for (int p = 0; p < 8; ++p) {
            float4 a = a_cur[p];
            uint2 pk;
            pk.x = (unsigned)f2bf(a.x) | ((unsigned)f2bf(a.y) << 16);
            pk.y = (unsigned)f2bf(a.z) | ((unsigned)f2bf(a.w) << 16);
            *(uint2*)&As[rb + p * 16][cg * 4] = pk;
        }
        {
            const uint4* src = (const uint4*)(Wt + (size_t)wrow * K + k0 + wh * 32);
#pragma unroll
            for (int q = 0; q < 4; ++q)
                *(uint4*)&Bs[wrow][wh * 32 + q * 8] = src[q];
        }
        __syncthreads();
        if (k0 + 64 < K) loadA(k0 + 64, a_nxt);
#pragma unroll
        for (int ks = 0; ks < 2; ++ks) {
            bf16x8 af[4], bfr[4];
#pragma unroll
            for (int i = 0; i < 4; ++i)
                af[i] = *(const bf16x8*)&As[wm + i * 16 + (lane & 15)][ks * 32 + (lane >> 4) * 8];
#pragma unroll
            for (int i = 0; i < 4; ++i)
                bfr[i] = *(const bf16x8*)&Bs[wn + i * 16 + (lane & 15)][ks * 32 + (lane >> 4) * 8];
#pragma unroll
            for (int mi = 0; mi < 4; ++mi)
#pragma unroll
                for (int ni = 0; ni < 4; ++ni)
                    acc[mi][ni] = __builtin_amdgcn_mfma_f32_16x16x32_bf16(
                        af[mi], bfr[ni], acc[mi][ni], 0, 0, 0);
        }
        __syncthreads();
        if (k0 + 64 < K) {
#pragma unroll
            for (int p = 0; p < 8; ++p) a_cur[p] = a_nxt[p];
        }
    }

    // epilogue: C/D frag layout col=lane&15, row=(lane>>4)*4+reg; emit fp8(dinv*acc)
#pragma unroll
    for (int mi = 0; mi < 4; ++mi) {
#pragma unroll
        for (int j = 0; j < 4; ++j) {
            int gr = m0 + wm + mi * 16 + (lane >> 4) * 4 + j;
            if (gr < M) {
                float dv = dinv[gr];
#pragma unroll
                for (int ni = 0; ni < 4; ++ni) {
                    int gc = wn + ni * 16 + (lane & 15);
                    Cout[(size_t)gr * HD + gc] = f2fp8(acc[mi][ni][j] * dv);
                }
            }
        }
    }
}

// ---------------------------------------------------------------------------
// k_a fused: weight transpose+convert | graph boundaries | edge bucketing.
// Buckets write to FIXED slots ebuf[c][r][0..SLOT) via LDS cursors — no
// prefix pass required. All blocks light (512B LDS) — fusion-safe (r10).
constexpr int KA_W = 128 * (IND + HD) / 256; // 256
constexpr int KA_G = (NN + 255) / 256;       // 391
__global__ __launch_bounds__(256) void k_a(const float* __restrict__ W1,
                                           const float* __restrict__ W2,
                                           unsigned short* __restrict__ W1t,
                                           unsigned short* __restrict__ W2t,
                                           const int* __restrict__ batch,
                                           int* __restrict__ gstart,
                                           const int* __restrict__ ei,
                                           int* __restrict__ ebuf,
                                           int* __restrict__ cnt2) {
    __shared__ int cur[NR];
    int bid = blockIdx.x;
    int t = threadIdx.x;
    if (bid < KA_W) {
        int id = bid * 256 + t;
        if (id < 128 * IND) {
            int n = id / IND, k = id - n * IND;
            W1t[id] = f2bf(W1[(size_t)k * HD + n]);
        } else {
            int id2 = id - 128 * IND;
            int n = id2 >> 7, k = id2 & 127;
            W2t[id2] = f2bf(W2[(size_t)k * HD + n]);
        }
        return;
    }
    if (bid < KA_W + KA_G) {
        int i = (bid - KA_W) * 256 + t;
        if (i < NN) {
            int b = batch[i];
            int prev = (i == 0) ? -1 : batch[i - 1];
            for (int g = prev + 1; g <= b; ++g) gstart[g] = i;
            if (i == NN - 1)
                for (int g = b + 1; g <= NG; ++g) gstart[g] = NN;
        }
        return;
    }
    int c = bid - KA_W - KA_G;
    if (t < NR) cur[t] = 0;
    __syncthreads();
    int e0 = c * CHUNK_E;
    for (int k = t; k < CHUNK_E; k += 256) {
        int e = e0 + k;
        int sv = ei[e];
        int d  = ei[NE + e];
        int r  = d / RSPAN;
        int i  = atomicAdd(&cur[r], 1);
        if (i < SLOT)
            ebuf[(size_t)c * (NR * SLOT) + r * SLOT + i] = ((d - r * RSPAN) << 17) | sv;
    }
    __syncthreads();
    if (t < NR) cnt2[c * NR + t] = min(cur[t], SLOT);
}

// ---------------------------------------------------------------------------
// k_b: one block per range. Derives its global edge base by summing all of
// cnt2 (400KB, L2-resident), packs its bucket entries into LDS once, counts
// per-node degrees, scans -> row_ptr + dinv, scatters csr_src. No global
// atomics; one global read of bucket data.
__global__ __launch_bounds__(1024) void k_b(const int* __restrict__ ebuf,
                                            const int* __restrict__ cnt2,
                                            int* __restrict__ row_ptr,
                                            float* __restrict__ dinv,
                                            int* __restrict__ csr_src) {
    __shared__ int Tl[NR];
    __shared__ int cntc[CHUNKS];
    __shared__ int segoff[CHUNKS];
    __shared__ int s[1024];
    __shared__ int entries[ENT_MAX];
    __shared__ int cnt[RSPAN];
    const int r = blockIdx.x, t = threadIdx.x;

    // range totals -> global edge base (es)
    if (t < NR) Tl[t] = 0;
    __syncthreads();
    for (int idx = t; idx < CHUNKS * NR; idx += 1024)
        atomicAdd(&Tl[idx & (NR - 1)], cnt2[idx]);
    __syncthreads();
    for (int off = 1; off < NR; off <<= 1) {
        int xv = (t >= off && t < NR) ? Tl[t - off] : 0;
        __syncthreads();
        if (t < NR) Tl[t] += xv;
        __syncthreads();
    }
    const int es = (r == 0) ? 0 : Tl[r - 1];

    // column-r counts + exclusive scan -> packed segment offsets
    for (int c = t; c < CHUNKS; c += 1024) cntc[c] = cnt2[c * NR + r];
    __syncthreads();
    int v = (t < CHUNKS) ? cntc[t] : 0;
    s[t] = v;
    __syncthreads();
    for (int off = 1; off < 1024; off <<= 1) {
        int xv = (t >= off) ? s[t - off] : 0;
        __syncthreads();
        s[t] += xv;
        __syncthreads();
    }
    if (t < CHUNKS) segoff[t] = s[t] - v;
    int EE = s[1023];
    if (EE > ENT_MAX) EE = ENT_MAX;
    __syncthreads();

    // pack: 16 segments in flight, 64 lanes each (coalesced 256B reads)
    for (int cb = 0; cb < CHUNKS; cb += 16) {
        int c = cb + (t >> 6);
        int lane = t & 63;
        int n = cntc[c];
        int p = segoff[c] + lane;
        if (lane < n && p < ENT_MAX)
            entries[p] = ebuf[(size_t)c * (NR * SLOT) + r * SLOT + lane];
    }
    const int lo = r * RSPAN;
    const int hi = min(lo + RSPAN, NN);
    const int span = hi - lo;
    if (t < span) cnt[t] = 0;
    __syncthreads();

    // per-node degrees
    for (int i = t; i < EE; i += 1024)
        atomicAdd(&cnt[entries[i] >> 17], 1);
    __syncthreads();
    int deg = (t < span) ? cnt[t] : 0;
    s[t] = deg;
    __syncthreads();
    for (int off = 1; off < 1024; off <<= 1) {
        int xv = (t >= off) ? s[t - off] : 0;
        __syncthreads();
        s[t] += xv;
        __syncthreads();
    }
    int base = es + s[t] - deg;
    if (t < span) {
        row_ptr[lo + t] = base;
        dinv[lo + t] = rsqrtf((float)deg + 1.0f);
    }
    __syncthreads();
    if (t < span) cnt[t] = base;   // reuse as cursors
    __syncthreads();
    for (int i = t; i < EE; i += 1024) {
        int ev = entries[i];
        int pos = atomicAdd(&cnt[ev >> 17], 1);
        csr_src[pos] = ev & 0x1FFFF;
    }
    if (r == 0 && t == 0) row_ptr[NN] = NE;
}

// ---------------------------------------------------------------------------
// gather over fp8 rows, fp32 accumulate. agg = dinv[n]*(hs[n] + sum_e hs[src]).
// OUTMODE 1 (layer 1): out fp8 = relu(agg + bias[c])  (feeds GEMM2 directly)
// OUTMODE 2 (layer 2): out fp8 = agg                   (feeds pool)
template <int OUTMODE>
__global__ __launch_bounds__(256) void k_gather(const int* __restrict__ row_ptr,
                                                const int* __restrict__ csr_src,
                                                const float* __restrict__ dinv,
                                                const unsigned char* __restrict__ hs,
                                                const float* __restrict__ bias,
                                                unsigned char* __restrict__ out8) {
    int gid = blockIdx.x * 256 + threadIdx.x;
    int node = gid >> 5;
    int l = threadIdx.x & 31;
    if (node >= NN) return;
    int start = row_ptr[node];
    int end   = row_ptr[node + 1];
    unsigned u0 = *(const unsigned*)(hs + (size_t)node * HD + l * 4);
    f32x2 lo = __builtin_amdgcn_cvt_pk_f32_fp8((int)u0, false);
    f32x2 hi = __builtin_amdgcn_cvt_pk_f32_fp8((int)u0, true);
    float4 acc;
    acc.x = lo[0]; acc.y = lo[1]; acc.z = hi[0]; acc.w = hi[1];
    for (int eb = start; eb < end; eb += 32) {
        int idx = eb + l;
        int src = 0;
        if (idx < end) src = csr_src[idx];
        int n = min(32, end - eb);
#pragma unroll 8
        for (int j = 0; j < n; ++j) {
            int s = __shfl(src, j, 32);
            unsigned u = *(const unsigned*)(hs + (size_t)s * HD + l * 4);
            f32x2 l2 = __builtin_amdgcn_cvt_pk_f32_fp8((int)u, false);
            f32x2 h2 = __builtin_amdgcn_cvt_pk_f32_fp8((int)u, true);
            acc.x += l2[0];
            acc.y += l2[1];
            acc.z += h2[0];
            acc.w += h2[1];
        }
    }
    float dv = dinv[node];
    acc.x *= dv; acc.y *= dv; acc.z *= dv; acc.w *= dv;
    if (OUTMODE == 1) {
        float4 bv = *(const float4*)(bias + l * 4);
        acc.x = fmaxf(acc.x + bv.x, 0.0f);
        acc.y = fmaxf(acc.y + bv.y, 0.0f);
        acc.z = fmaxf(acc.z + bv.z, 0.0f);
        acc.w = fmaxf(acc.w + bv.w, 0.0f);
    }
    int w = __builtin_amdgcn_cvt_pk_fp8_f32(acc.x, acc.y, 0, false);
    w = __builtin_amdgcn_cvt_pk_fp8_f32(acc.z, acc.w, w, true);
    *(unsigned*)(out8 + (size_t)node * HD + l * 4) = (unsigned)w;
}

// ---------------------------------------------------------------------------
// pool + head fused: one block per graph (sorted batch -> contiguous ranges).
// acc2 is fp8. 1024 threads = 32 row-parities x 32 channel-groups (4 ch).
__global__ __launch_bounds__(1024) void k_pool2(const unsigned char* __restrict__ acc2,
                                                const float* __restrict__ b2,
                                                const int* __restrict__ gstart,
                                                const float* __restrict__ fcw,
                                                const float* __restrict__ fcb,
                                                float* __restrict__ out) {
    int g = blockIdx.x;
    int tid = threadIdx.x;
    int cg = tid & 31;              // channel group: channels cg*4..+3
    int par = tid >> 5;             // row parity 0..31
    int s = gstart[g];
    int e = gstart[g + 1];
    float4 bv = *(const float4*)(b2 + cg * 4);
    float4 sum = {0.f, 0.f, 0.f, 0.f};
    for (int i = s + par; i < e; i += 32) {
        unsigned u = *(const unsigned*)(acc2 + (size_t)i * HD + cg * 4);
        f32x2 lo = __builtin_amdgcn_cvt_pk_f32_fp8((int)u, false);
        f32x2 hi = __builtin_amdgcn_cvt_pk_f32_fp8((int)u, true);
        sum.x += fmaxf(lo[0] + bv.x, 0.0f);
        sum.y += fmaxf(lo[1] + bv.y, 0.0f);
        sum.z += fmaxf(hi[0] + bv.z, 0.0f);
        sum.w += fmaxf(hi[1] + bv.w, 0.0f);
    }
    __shared__ float ps[32][128];
    *(float4*)&ps[par][cg * 4] = sum;
    __syncthreads();

    float a0 = 0.0f, a1 = 0.0f;
    if (tid < 128) {
        int c = tid;
        float p = 0.0f;
#pragma unroll
        for (int q = 0; q < 32; ++q) p += ps[q][c];
        p /= fmaxf((float)(e - s), 1.0f);
        a0 = p * fcw[c * 2 + 0];
        a1 = p * fcw[c * 2 + 1];
    }
#pragma unroll
    for (int off = 32; off; off >>= 1) {
        a0 += __shfl_down(a0, off, 64);
        a1 += __shfl_down(a1, off, 64);
    }
    __shared__ float r0[2], r1[2];
    if (tid < 128 && (tid & 63) == 0) { r0[tid >> 6] = a0; r1[tid >> 6] = a1; }
    __syncthreads();
    if (tid == 0) {
        float l0 = r0[0] + r0[1] + fcb[0];
        float l1 = r1[0] + r1[1] + fcb[1];
        float m = fmaxf(l0, l1);
        float lse = m + logf(__expf(l0 - m) + __expf(l1 - m));
        out[g * 2 + 0] = l0 - lse;
        out[g * 2 + 1] = l1 - lse;
    }
}

// ---------------------------------------------------------------------------
extern "C" void kernel_launch(void* const* d_in, const int* in_sizes, int n_in,
                              void* d_out, int out_size, void* d_ws, size_t ws_size,
                              hipStream_t stream) {
    const float* x    = (const float*)d_in[0];
    const int*   ei   = (const int*)d_in[1];   // [2][NE]
    const int*   batch= (const int*)d_in[2];   // [NN] (sorted)
    const float* W1   = (const float*)d_in[3];
    const float* b1   = (const float*)d_in[4];
    const float* W2   = (const float*)d_in[5];
    const float* b2   = (const float*)d_in[6];
    const float* fcw  = (const float*)d_in[7];
    const float* fcb  = (const float*)d_in[8];
    float* out = (float*)d_out;

    // workspace layout (all offsets >=8B-aligned)
    char* ws = (char*)d_ws;
    float* dinv    = (float*)ws;                        ws += 100352 * 4;
    unsigned char* bufA8 = (unsigned char*)ws;          ws += (size_t)NN * HD;      // fp8 hs
    unsigned char* bufB8 = (unsigned char*)ws;          ws += (size_t)NN * HD;      // fp8 relu(agg1+b1)
    unsigned char* bufC8 = (unsigned char*)ws;          ws += (size_t)NN * HD;      // fp8 agg2
    int*   row_ptr = (int*)ws;                          ws += 100352 * 4;
    int*   gstart  = (int*)ws;                          ws += 520 * 4;
    unsigned short* W1t = (unsigned short*)ws;          ws += (size_t)128 * IND * 2;
    unsigned short* W2t = (unsigned short*)ws;          ws += (size_t)128 * HD * 2;
    int*   csr_src = (int*)ws;                          ws += (size_t)NE * 4;
    int*   cnt2    = (int*)ws;                          ws += (size_t)CHUNKS * NR * 4;
    int*   ebuf    = (int*)ws;                          ws += (size_t)CHUNKS * NR * SLOT * 4; // 26.2MB

    const int mblk = (NN + 127) / 128;           // 782
    const int wblk = (NN * 32 + 255) / 256;      // 12500

    // k_a: wprep | gbound | fixed-slot edge bucketing (+ per-bucket counts)
    k_a<<<KA_W + KA_G + CHUNKS, 256, 0, stream>>>(W1, W2, W1t, W2t, batch, gstart,
                                                  ei, ebuf, cnt2);

    // k_b: per-range CSR build (row_ptr, dinv, csr_src) — no global atomics
    k_b<<<NR, 1024, 0, stream>>>(ebuf, cnt2, row_ptr, dinv, csr_src);

    // layer 1: hs1 = fp8(dinv*(x@W1)) -> bufA8 ; gather (+b1, relu) -> bufB8 (fp8)
    k_gemm_mfma<IND, 0><<<mblk, 256, 0, stream>>>(x, W1t, dinv, bufA8, NN);
    k_gather<1><<<wblk, 256, 0, stream>>>(row_ptr, csr_src, dinv, bufA8, b1, bufB8);

    // layer 2: hs2 = fp8(dinv*(bufB8@W2)) -> bufA8 ; gather -> bufC8 (fp8)
    k_gemm_mfma<HD, 2><<<mblk, 256, 0, stream>>>(bufB8, W2t, dinv, bufA8, NN);
    k_gather<2><<<wblk, 256, 0, stream>>>(row_ptr, csr_src, dinv, bufA8, nullptr, bufC8);

    // fused pool + head (fp8 input)
    k_pool2<<<NG, 1024, 0, stream>>>(bufC8, b2, gstart, fcw, fcb, out);
}

// Round 15
// 230.850 us; speedup vs baseline: 1.1291x; 1.1291x over previous
//
#include <hip/hip_runtime.h>
#include <hip/hip_bf16.h>

// Problem constants
constexpr int NN = 100000;       // nodes
constexpr int NE = 1600000;      // edges
constexpr int NG = 512;          // graphs
constexpr int IND = 384;         // in dim
constexpr int HD  = 128;         // hidden dim

// CSR bucket-sort geometry (no global atomics anywhere)
constexpr int NR      = 128;             // node ranges
constexpr int RSPAN   = 782;             // nodes per range (128*782 >= NN)
constexpr int CHUNKS  = 800;             // edge chunks
constexpr int CHUNK_E = NE / CHUNKS;     // 2000 edges per chunk

typedef short bf16x8 __attribute__((ext_vector_type(8)));
typedef float f32x4  __attribute__((ext_vector_type(4)));
typedef float f32x2  __attribute__((ext_vector_type(2)));

__device__ __forceinline__ unsigned short f2bf(float x) {
    unsigned int u = __builtin_bit_cast(unsigned int, x);
    u = (u + 0x7FFFu + ((u >> 16) & 1u)) >> 16;   // RNE
    return (unsigned short)u;
}
__device__ __forceinline__ float bf2f(unsigned short v) {
    return __builtin_bit_cast(float, (unsigned int)v << 16);
}
// fp8 e4m3 (OCP) encode/decode via gfx950 HW converts
__device__ __forceinline__ unsigned char f2fp8(float v) {
    return (unsigned char)(__builtin_amdgcn_cvt_pk_fp8_f32(v, 0.0f, 0, false) & 0xFF);
}

// ---------------------------------------------------------------------------
// MFMA bf16 GEMM: Cout[M x 128](fp8 e4m3) = dinv[row] * (A @ Wt^T)
// AMODE: 0 = A fp32 ; 2 = A fp8 e4m3. Wt is [128][K] bf16.
// 128x128 tile, BK=64, 4 waves each owning a 64x64 quadrant (4x4 16x16 frags).
// Register-prefetch of the next K-tile's A overlaps HBM latency with MFMA.
// NOTE (r10 lesson): keep UNFUSED from scatter work — 37.9KB-LDS blocks cap
// occupancy and strangle latency-bound blocks co-scheduled with them.
// NOTE (r14 lesson): don't trade launch count for fat low-parallelism blocks;
// the 4-launch CSR chain with full-occupancy kernels beats a 2-launch one
// with 128 x 68KB-LDS blocks (238 vs 261 us).
template <int K, int AMODE>
__global__ __launch_bounds__(256) void k_gemm_mfma(const void* __restrict__ Av,
                                                   const unsigned short* __restrict__ Wt,
                                                   const float* __restrict__ dinv,
                                                   unsigned char* __restrict__ Cout,
                                                   int M) {
    __shared__ unsigned short As[128][72];   // rows padded: stride 144B
    __shared__ unsigned short Bs[128][72];   // Bs[n][k]
    const int tid  = threadIdx.x;
    const int lane = tid & 63;
    const int wid  = tid >> 6;
    const int wm   = (wid & 1) * 64;
    const int wn   = (wid >> 1) * 64;
    const int m0   = blockIdx.x * 128;

    f32x4 acc[4][4];
#pragma unroll
    for (int i = 0; i < 4; ++i)
#pragma unroll
        for (int j = 0; j < 4; ++j) acc[i][j] = f32x4{0.f, 0.f, 0.f, 0.f};

    const int cg = tid & 15;      // A col group (4 elems)
    const int rb = tid >> 4;      // A row base 0..15
    const int wrow = tid >> 1;    // Wt row 0..127
    const int wh   = tid & 1;     // Wt 32-col half

    float4 a_cur[8], a_nxt[8];
    auto loadA = [&](int k0, float4* dst) {
#pragma unroll
        for (int p = 0; p < 8; ++p) {
            int gr = m0 + rb + p * 16; if (gr > M - 1) gr = M - 1;
            if (AMODE == 0) {
                dst[p] = *(const float4*)((const float*)Av + (size_t)gr * K + k0 + cg * 4);
            } else {
                unsigned u = *(const unsigned*)((const unsigned char*)Av +
                                                (size_t)gr * K + k0 + cg * 4);
                f32x2 lo = __builtin_amdgcn_cvt_pk_f32_fp8((int)u, false);
                f32x2 hi = __builtin_amdgcn_cvt_pk_f32_fp8((int)u, true);
                dst[p].x = lo[0]; dst[p].y = lo[1]; dst[p].z = hi[0]; dst[p].w = hi[1];
            }
        }
    };

    loadA(0, a_cur);
    for (int k0 = 0; k0 < K; k0 += 64) {
#pragma unroll
        for (int p = 0; p < 8; ++p) {
            float4 a = a_cur[p];
            uint2 pk;
            pk.x = (unsigned)f2bf(a.x) | ((unsigned)f2bf(a.y) << 16);
            pk.y = (unsigned)f2bf(a.z) | ((unsigned)f2bf(a.w) << 16);
            *(uint2*)&As[rb + p * 16][cg * 4] = pk;
        }
        {
            const uint4* src = (const uint4*)(Wt + (size_t)wrow * K + k0 + wh * 32);
#pragma unroll
            for (int q = 0; q < 4; ++q)
                *(uint4*)&Bs[wrow][wh * 32 + q * 8] = src[q];
        }
        __syncthreads();
        if (k0 + 64 < K) loadA(k0 + 64, a_nxt);
#pragma unroll
        for (int ks = 0; ks < 2; ++ks) {
            bf16x8 af[4], bfr[4];
#pragma unroll
            for (int i = 0; i < 4; ++i)
                af[i] = *(const bf16x8*)&As[wm + i * 16 + (lane & 15)][ks * 32 + (lane >> 4) * 8];
#pragma unroll
            for (int i = 0; i < 4; ++i)
                bfr[i] = *(const bf16x8*)&Bs[wn + i * 16 + (lane & 15)][ks * 32 + (lane >> 4) * 8];
#pragma unroll
            for (int mi = 0; mi < 4; ++mi)
#pragma unroll
                for (int ni = 0; ni < 4; ++ni)
                    acc[mi][ni] = __builtin_amdgcn_mfma_f32_16x16x32_bf16(
                        af[mi], bfr[ni], acc[mi][ni], 0, 0, 0);
        }
        __syncthreads();
        if (k0 + 64 < K) {
#pragma unroll
            for (int p = 0; p < 8; ++p) a_cur[p] = a_nxt[p];
        }
    }

    // epilogue: C/D frag layout col=lane&15, row=(lane>>4)*4+reg; emit fp8(dinv*acc)
#pragma unroll
    for (int mi = 0; mi < 4; ++mi) {
#pragma unroll
        for (int j = 0; j < 4; ++j) {
            int gr = m0 + wm + mi * 16 + (lane >> 4) * 4 + j;
            if (gr < M) {
                float dv = dinv[gr];
#pragma unroll
                for (int ni = 0; ni < 4; ++ni) {
                    int gc = wn + ni * 16 + (lane & 15);
                    Cout[(size_t)gr * HD + gc] = f2fp8(acc[mi][ni][j] * dv);
                }
            }
        }
    }
}

// ---------------------------------------------------------------------------
// P0 fused prologue: weight transpose+convert | graph boundaries |
// F1: per-chunk range histogram (LDS atomics only)
constexpr int P0_W = 128 * (IND + HD) / 256; // 256
constexpr int P0_G = (NN + 255) / 256;       // 391
__global__ __launch_bounds__(256) void k_p0(const float* __restrict__ W1,
                                            const float* __restrict__ W2,
                                            unsigned short* __restrict__ W1t,
                                            unsigned short* __restrict__ W2t,
                                            const int* __restrict__ batch,
                                            int* __restrict__ gstart,
                                            const int* __restrict__ ei,
                                            int* __restrict__ cnt2) {
    __shared__ int hist[NR];
    int bid = blockIdx.x;
    int t = threadIdx.x;
    if (bid < P0_W) {
        int id = bid * 256 + t;
        if (id < 128 * IND) {
            int n = id / IND, k = id - n * IND;
            W1t[id] = f2bf(W1[(size_t)k * HD + n]);
        } else {
            int id2 = id - 128 * IND;
            int n = id2 >> 7, k = id2 & 127;
            W2t[id2] = f2bf(W2[(size_t)k * HD + n]);
        }
    } else if (bid < P0_W + P0_G) {
        int i = (bid - P0_W) * 256 + t;
        if (i < NN) {
            int b = batch[i];
            int prev = (i == 0) ? -1 : batch[i - 1];
            for (int g = prev + 1; g <= b; ++g) gstart[g] = i;
            if (i == NN - 1)
                for (int g = b + 1; g <= NG; ++g) gstart[g] = NN;
        }
    } else {
        int c = bid - P0_W - P0_G;
        if (t < NR) hist[t] = 0;
        __syncthreads();
        int e0 = c * CHUNK_E;
        for (int k = t; k < CHUNK_E; k += 256)
            atomicAdd(&hist[ei[NE + e0 + k] / RSPAN], 1);
        __syncthreads();
        if (t < NR) cnt2[c * NR + t] = hist[t];
    }
}

// F2: per-range exclusive scan of cnt2 over chunks; totals -> T
__global__ __launch_bounds__(1024) void k_f2a(const int* __restrict__ cnt2,
                                              int* __restrict__ base2,
                                              int* __restrict__ T) {
    __shared__ int s[1024];
    int r = blockIdx.x, t = threadIdx.x;
    int v = (t < CHUNKS) ? cnt2[t * NR + r] : 0;
    s[t] = v;
    __syncthreads();
    for (int off = 1; off < 1024; off <<= 1) {
        int x = (t >= off) ? s[t - off] : 0;
        __syncthreads();
        s[t] += x;
        __syncthreads();
    }
    if (t < CHUNKS) base2[t * NR + r] = s[t] - v;
    if (t == 1023) T[r] = s[1023];
}

// ---------------------------------------------------------------------------
// F3: bucket edges by range at deterministic offsets (in-block scan of T
// gives range bases; LDS cursors). Packed entry: (local_dst << 17) | src.
__global__ __launch_bounds__(256) void k_f3(const int* __restrict__ ei,
                                            const int* __restrict__ base2,
                                            const int* __restrict__ T,
                                            int* __restrict__ ebuf) {
    __shared__ int cur[NR];
    __shared__ int sT[NR];
    int c = blockIdx.x;
    int t = threadIdx.x;
    int Tv = (t < NR) ? T[t] : 0;
    if (t < NR) sT[t] = Tv;
    __syncthreads();
    for (int off = 1; off < NR; off <<= 1) {
        int xv = (t >= off && t < NR) ? sT[t - off] : 0;
        __syncthreads();
        if (t < NR) sT[t] += xv;
        __syncthreads();
    }
    if (t < NR) cur[t] = (sT[t] - Tv) + base2[c * NR + t];
    __syncthreads();
    int e0 = c * CHUNK_E;
    for (int k = t; k < CHUNK_E; k += 256) {
        int e = e0 + k;
        int sv = ei[e];
        int d = ei[NE + e];
        int r = d / RSPAN;
        int pos = atomicAdd(&cur[r], 1);
        ebuf[pos] = ((d - r * RSPAN) << 17) | sv;
    }
}

// F4: one block per range; per-node degree (LDS), LDS scan -> row_ptr + dinv,
// then scatter bucketed edges into exact CSR slots via LDS cursors.
__global__ __launch_bounds__(1024) void k_f4(const int* __restrict__ ebuf,
                                             const int* __restrict__ T,
                                             int* __restrict__ row_ptr,
                                             float* __restrict__ dinv,
                                             int* __restrict__ csr_src) {
    __shared__ int cnt[RSPAN];
    __shared__ int s[1024];
    __shared__ int sT[NR];
    int r = blockIdx.x, t = threadIdx.x;
    if (t < NR) sT[t] = T[t];
    __syncthreads();
    for (int off = 1; off < NR; off <<= 1) {
        int xv = (t >= off && t < NR) ? sT[t - off] : 0;
        __syncthreads();
        if (t < NR) sT[t] += xv;
        __syncthreads();
    }
    int es = (r == 0) ? 0 : sT[r - 1];
    int ee = sT[r];
    int lo = r * RSPAN;
    int hi = min(lo + RSPAN, NN);
    int span = hi - lo;
    if (t < span) cnt[t] = 0;
    __syncthreads();
    for (int e = es + t; e < ee; e += 1024)
        atomicAdd(&cnt[ebuf[e] >> 17], 1);
    __syncthreads();
    int v = (t < span) ? cnt[t] : 0;
    s[t] = v;
    __syncthreads();
    for (int off = 1; off < 1024; off <<= 1) {
        int xv = (t >= off) ? s[t - off] : 0;
        __syncthreads();
        s[t] += xv;
        __syncthreads();
    }
    int base = es + s[t] - v;
    if (t < span) {
        row_ptr[lo + t] = base;
        dinv[lo + t] = rsqrtf((float)v + 1.0f);
    }
    __syncthreads();
    if (t < span) cnt[t] = base;   // reuse as cursors
    __syncthreads();
    for (int e = es + t; e < ee; e += 1024) {
        int ev = ebuf[e];
        int pos = atomicAdd(&cnt[ev >> 17], 1);
        csr_src[pos] = ev & 0x1FFFF;
    }
    if (r == 0 && t == 0) row_ptr[NN] = NE;
}

// ---------------------------------------------------------------------------
// gather over fp8 rows, fp32 accumulate. agg = dinv[n]*(hs[n] + sum_e hs[src]).
// OUTMODE 1 (layer 1): out fp8 = relu(agg + bias[c])  (feeds GEMM2 directly)
// OUTMODE 2 (layer 2): out fp8 = agg                   (feeds pool)
template <int OUTMODE>
__global__ __launch_bounds__(256) void k_gather(const int* __restrict__ row_ptr,
                                                const int* __restrict__ csr_src,
                                                const float* __restrict__ dinv,
                                                const unsigned char* __restrict__ hs,
                                                const float* __restrict__ bias,
                                                unsigned char* __restrict__ out8) {
    int gid = blockIdx.x * 256 + threadIdx.x;
    int node = gid >> 5;
    int l = threadIdx.x & 31;
    if (node >= NN) return;
    int start = row_ptr[node];
    int end   = row_ptr[node + 1];
    unsigned u0 = *(const unsigned*)(hs + (size_t)node * HD + l * 4);
    f32x2 lo = __builtin_amdgcn_cvt_pk_f32_fp8((int)u0, false);
    f32x2 hi = __builtin_amdgcn_cvt_pk_f32_fp8((int)u0, true);
    float4 acc;
    acc.x = lo[0]; acc.y = lo[1]; acc.z = hi[0]; acc.w = hi[1];
    for (int eb = start; eb < end; eb += 32) {
        int idx = eb + l;
        int src = 0;
        if (idx < end) src = csr_src[idx];
        int n = min(32, end - eb);
#pragma unroll 8
        for (int j = 0; j < n; ++j) {
            int s = __shfl(src, j, 32);
            unsigned u = *(const unsigned*)(hs + (size_t)s * HD + l * 4);
            f32x2 l2 = __builtin_amdgcn_cvt_pk_f32_fp8((int)u, false);
            f32x2 h2 = __builtin_amdgcn_cvt_pk_f32_fp8((int)u, true);
            acc.x += l2[0];
            acc.y += l2[1];
            acc.z += h2[0];
            acc.w += h2[1];
        }
    }
    float dv = dinv[node];
    acc.x *= dv; acc.y *= dv; acc.z *= dv; acc.w *= dv;
    if (OUTMODE == 1) {
        float4 bv = *(const float4*)(bias + l * 4);
        acc.x = fmaxf(acc.x + bv.x, 0.0f);
        acc.y = fmaxf(acc.y + bv.y, 0.0f);
        acc.z = fmaxf(acc.z + bv.z, 0.0f);
        acc.w = fmaxf(acc.w + bv.w, 0.0f);
    }
    int w = __builtin_amdgcn_cvt_pk_fp8_f32(acc.x, acc.y, 0, false);
    w = __builtin_amdgcn_cvt_pk_fp8_f32(acc.z, acc.w, w, true);
    *(unsigned*)(out8 + (size_t)node * HD + l * 4) = (unsigned)w;
}

// ---------------------------------------------------------------------------
// pool + head fused: one block per graph (sorted batch -> contiguous ranges).
// acc2 is fp8. 1024 threads = 32 row-parities x 32 channel-groups (4 ch).
__global__ __launch_bounds__(1024) void k_pool2(const unsigned char* __restrict__ acc2,
                                                const float* __restrict__ b2,
                                                const int* __restrict__ gstart,
                                                const float* __restrict__ fcw,
                                                const float* __restrict__ fcb,
                                                float* __restrict__ out) {
    int g = blockIdx.x;
    int tid = threadIdx.x;
    int cg = tid & 31;              // channel group: channels cg*4..+3
    int par = tid >> 5;             // row parity 0..31
    int s = gstart[g];
    int e = gstart[g + 1];
    float4 bv = *(const float4*)(b2 + cg * 4);
    float4 sum = {0.f, 0.f, 0.f, 0.f};
    for (int i = s + par; i < e; i += 32) {
        unsigned u = *(const unsigned*)(acc2 + (size_t)i * HD + cg * 4);
        f32x2 lo = __builtin_amdgcn_cvt_pk_f32_fp8((int)u, false);
        f32x2 hi = __builtin_amdgcn_cvt_pk_f32_fp8((int)u, true);
        sum.x += fmaxf(lo[0] + bv.x, 0.0f);
        sum.y += fmaxf(lo[1] + bv.y, 0.0f);
        sum.z += fmaxf(hi[0] + bv.z, 0.0f);
        sum.w += fmaxf(hi[1] + bv.w, 0.0f);
    }
    __shared__ float ps[32][128];
    *(float4*)&ps[par][cg * 4] = sum;
    __syncthreads();

    float a0 = 0.0f, a1 = 0.0f;
    if (tid < 128) {
        int c = tid;
        float p = 0.0f;
#pragma unroll
        for (int q = 0; q < 32; ++q) p += ps[q][c];
        p /= fmaxf((float)(e - s), 1.0f);
        a0 = p * fcw[c * 2 + 0];
        a1 = p * fcw[c * 2 + 1];
    }
#pragma unroll
    for (int off = 32; off; off >>= 1) {
        a0 += __shfl_down(a0, off, 64);
        a1 += __shfl_down(a1, off, 64);
    }
    __shared__ float r0[2], r1[2];
    if (tid < 128 && (tid & 63) == 0) { r0[tid >> 6] = a0; r1[tid >> 6] = a1; }
    __syncthreads();
    if (tid == 0) {
        float l0 = r0[0] + r0[1] + fcb[0];
        float l1 = r1[0] + r1[1] + fcb[1];
        float m = fmaxf(l0, l1);
        float lse = m + logf(__expf(l0 - m) + __expf(l1 - m));
        out[g * 2 + 0] = l0 - lse;
        out[g * 2 + 1] = l1 - lse;
    }
}

// ---------------------------------------------------------------------------
extern "C" void kernel_launch(void* const* d_in, const int* in_sizes, int n_in,
                              void* d_out, int out_size, void* d_ws, size_t ws_size,
                              hipStream_t stream) {
    const float* x    = (const float*)d_in[0];
    const int*   ei   = (const int*)d_in[1];   // [2][NE]
    const int*   batch= (const int*)d_in[2];   // [NN] (sorted)
    const float* W1   = (const float*)d_in[3];
    const float* b1   = (const float*)d_in[4];
    const float* W2   = (const float*)d_in[5];
    const float* b2   = (const float*)d_in[6];
    const float* fcw  = (const float*)d_in[7];
    const float* fcb  = (const float*)d_in[8];
    float* out = (float*)d_out;

    // workspace layout (all offsets >=8B-aligned)
    char* ws = (char*)d_ws;
    float* dinv    = (float*)ws;                        ws += 100352 * 4;
    unsigned char* bufA8 = (unsigned char*)ws;          ws += (size_t)NN * HD;      // fp8 hs
    unsigned char* bufB8 = (unsigned char*)ws;          ws += (size_t)NN * HD;      // fp8 relu(agg1+b1)
    unsigned char* bufC8 = (unsigned char*)ws;          ws += (size_t)NN * HD;      // fp8 agg2
    int*   row_ptr = (int*)ws;                          ws += 100352 * 4;
    int*   gstart  = (int*)ws;                          ws += 520 * 4;
    unsigned short* W1t = (unsigned short*)ws;          ws += (size_t)128 * IND * 2;
    unsigned short* W2t = (unsigned short*)ws;          ws += (size_t)128 * HD * 2;
    int*   csr_src = (int*)ws;                          ws += (size_t)NE * 4;
    int*   cnt2    = (int*)ws;                          ws += (size_t)CHUNKS * NR * 4;
    int*   base2   = (int*)ws;                          ws += (size_t)CHUNKS * NR * 4;
    int*   T       = (int*)ws;                          ws += NR * 4;
    int*   ebuf    = (int*)ws;                          ws += (size_t)NE * 4;

    const int mblk = (NN + 127) / 128;           // 782
    const int wblk = (NN * 32 + 255) / 256;      // 12500

    // prologue: wprep | gbound | F1 per-chunk range histograms (LDS only)
    k_p0<<<P0_W + P0_G + CHUNKS, 256, 0, stream>>>(W1, W2, W1t, W2t, batch, gstart, ei, cnt2);

    // F2: deterministic bucket bases
    k_f2a<<<NR, 1024, 0, stream>>>(cnt2, base2, T);

    // F3: bucket packed edges (standalone, high occupancy)
    k_f3<<<CHUNKS, 256, 0, stream>>>(ei, base2, T, ebuf);

    // F4: per-range degree+scan -> row_ptr,dinv; scatter -> csr_src
    k_f4<<<NR, 1024, 0, stream>>>(ebuf, T, row_ptr, dinv, csr_src);

    // layer 1: hs1 = fp8(dinv*(x@W1)) -> bufA8 ; gather (+b1, relu) -> bufB8 (fp8)
    k_gemm_mfma<IND, 0><<<mblk, 256, 0, stream>>>(x, W1t, dinv, bufA8, NN);
    k_gather<1><<<wblk, 256, 0, stream>>>(row_ptr, csr_src, dinv, bufA8, b1, bufB8);

    // layer 2: hs2 = fp8(dinv*(bufB8@W2)) -> bufA8 ; gather -> bufC8 (fp8)
    k_gemm_mfma<HD, 2><<<mblk, 256, 0, stream>>>(bufB8, W2t, dinv, bufA8, NN);
    k_gather<2><<<wblk, 256, 0, stream>>>(row_ptr, csr_src, dinv, bufA8, nullptr, bufC8);

    // fused pool + head (fp8 input)
    k_pool2<<<NG, 1024, 0, stream>>>(bufC8, b2, gstart, fcw, fcb, out);
}